// Round 16
// baseline (1189.155 us; speedup 1.0000x reference)
//
#include <hip/hip_runtime.h>

#define E_N 262144
#define T_N 1048576

typedef short  bf16x8  __attribute__((ext_vector_type(8)));
typedef float  f32x4   __attribute__((ext_vector_type(4)));

// wreg offsets (ushort units)
#define OFF_KJ    0
#define OFF_DOWN  16384
#define OFF_UP    24576
#define OFF_JI    32768
#define OFF_GU    49152
#define OFF_CN    65536
#define OFF_RB0   81920
#define OFF_RB1   98304
#define OFF_LIN   114688
#define OFF_RA00  131072
#define OFF_RA01  147456
#define OFF_RA10  163840
#define OFF_RA11  180224
#define OFF_END   196608   // W12 (f32[6][128]) follows
#define WREG_BYTES 524288u

// byte offsets inside the e2 slot (134217728 B)
#define OFFB_AGG   0u
#define OFFB_XKJ   33554432u
#define OFFB_WREG  67108864u
#define OFFB_CNT   67633152u
#define OFFB_POS   68683776u
#define OFFB_TRI   69732352u
#define OFFB_BS    73926656u
#define OFFB_BP    73927680u
#define OFFB_KJP   75497472u
#define OFFB_INV   79691776u

// fast silu: x * rcp(1 + e^-x)
__device__ __forceinline__ float silu_f(float x) {
  float e;
  asm("v_exp_f32_e32 %0, %1" : "=v"(e) : "v"(x * -1.44269504088896f));
  float r;
  asm("v_rcp_f32_e32 %0, %1" : "=v"(r) : "v"(1.0f + e));
  return x * r;
}

__device__ __forceinline__ f32x4 silu4(f32x4 v) {
  f32x4 r;
#pragma unroll
  for (int i = 0; i < 4; ++i) r[i] = silu_f(v[i]);
  return r;
}

__device__ __forceinline__ unsigned short f2bf(float f) {
  union { float f; unsigned int u; } v; v.f = f;
  unsigned int u = v.u;
  return (unsigned short)((u + 0x7fffu + ((u >> 16) & 1u)) >> 16);   // RNE
}
__device__ __forceinline__ float bf2f(unsigned short h) {
  union { unsigned int u; float f; } v; v.u = ((unsigned int)h) << 16;
  return v.f;
}

__device__ __forceinline__ unsigned cvtpk(float lo, float hi) {
  unsigned r;
  asm("v_cvt_pk_bf16_f32 %0, %1, %2" : "=v"(r) : "v"(lo), "v"(hi));
  return r;
}

// LDS-only barrier
__device__ __forceinline__ void lds_barrier() {
  asm volatile("s_waitcnt lgkmcnt(0)" ::: "memory");
  __builtin_amdgcn_s_barrier();
  __builtin_amdgcn_sched_barrier(0);
}

// ---- stage [NR][NC] f32 global tile -> swizzled bf16 LDS tile (cvt_pk) ----
template<int NC, int NR, int NTH>
__device__ __forceinline__ void stage_tile(const float* __restrict__ g, char* __restrict__ lds) {
  constexpr int RB = NC * 2;
  constexpr int C4 = NC / 4;
  for (int i = threadIdx.x; i < NR * C4; i += NTH) {
    int r = i / C4, c4 = i % C4;
    float4 v = *(const float4*)(g + (size_t)r * NC + c4 * 4);
    uint2 u;
    u.x = cvtpk(v.x, v.y);
    u.y = cvtpk(v.z, v.w);
    *(uint2*)(lds + r * RB + ((c4 * 8) ^ ((r & 7) << 4))) = u;
  }
}

// Fragment-major weight layout: frag idx = ((nt*KS + kk)*4 + kg)*128 + r15*8 + j

// ==== swapped GEMM: D[e][n].  A = W frags (global), B = X row frags (swizzled LDS) ====
// lane: e = e0 + r15 (LDS-local row), n = nt*16 + kg*4 + reg
template<int MREP, int KSTEPS, int RB>
__device__ __forceinline__ void mfma_gemm_T(const char* __restrict__ lds, int e0, int nt0,
                                            const unsigned short* __restrict__ WT, int lane,
                                            f32x4 (&acc)[MREP]) {
  const int kg = lane >> 4, r15 = lane & 15;
#pragma unroll
  for (int m = 0; m < MREP; ++m) acc[m] = (f32x4){0.f, 0.f, 0.f, 0.f};
  const int row = e0 + r15, sw = (row & 7) << 4;
  __builtin_amdgcn_s_setprio(1);
#pragma unroll
  for (int kk = 0; kk < KSTEPS; ++kk) {
    bf16x8 xb = *(const bf16x8*)(lds + row * RB + ((kk * 64 + kg * 16) ^ sw));
    bf16x8 wa[MREP];
#pragma unroll
    for (int m = 0; m < MREP; ++m)
      wa[m] = *(const bf16x8*)(WT + ((((nt0 + m) * KSTEPS + kk) * 4 + kg) << 7) + (r15 << 3));
#pragma unroll
    for (int m = 0; m < MREP; ++m)
      acc[m] = __builtin_amdgcn_mfma_f32_16x16x32_bf16(wa[m], xb, acc[m], 0, 0, 0);
  }
  __builtin_amdgcn_s_setprio(0);
}

// B rows straight from global (row = global edge index, stride RS shorts)
template<int MREP, int KSTEPS, int RS>
__device__ __forceinline__ void mfma_gemm_T_gB(const unsigned short* __restrict__ gB,
                                               size_t erow0, int nt0,
                                               const unsigned short* __restrict__ WT, int lane,
                                               f32x4 (&acc)[MREP]) {
  const int kg = lane >> 4, r15 = lane & 15;
#pragma unroll
  for (int m = 0; m < MREP; ++m) acc[m] = (f32x4){0.f, 0.f, 0.f, 0.f};
  const size_t row = erow0 + r15;
  __builtin_amdgcn_s_setprio(1);
#pragma unroll
  for (int kk = 0; kk < KSTEPS; ++kk) {
    bf16x8 xb = *(const bf16x8*)(gB + row * RS + kk * 32 + kg * 8);
    bf16x8 wa[MREP];
#pragma unroll
    for (int m = 0; m < MREP; ++m)
      wa[m] = *(const bf16x8*)(WT + ((((nt0 + m) * KSTEPS + kk) * 4 + kg) << 7) + (r15 << 3));
#pragma unroll
    for (int m = 0; m < MREP; ++m)
      acc[m] = __builtin_amdgcn_mfma_f32_16x16x32_bf16(wa[m], xb, acc[m], 0, 0, 0);
  }
  __builtin_amdgcn_s_setprio(0);
}

// ---- write MREP n-frags for edge e: one b64 per frag, contiguous [e][n0..n0+3] ----
template<int MREP, int RB>
__device__ __forceinline__ void write_cd_T(char* __restrict__ lds, int e0, int nbase, int lane,
                                           const f32x4 (&v)[MREP]) {
  const int kg = lane >> 4, r15 = lane & 15;
  const int row = e0 + r15, sw = (row & 7) << 4;
#pragma unroll
  for (int m = 0; m < MREP; ++m) {
    int off = (nbase + m * 16 + kg * 4) * 2;
    uint2 u;
    u.x = cvtpk(v[m][0], v[m][1]);
    u.y = cvtpk(v[m][2], v[m][3]);
    *(uint2*)(lds + row * RB + (off ^ sw)) = u;
  }
}

// ---- prep: weights -> fragment-major bf16; W12 = W_rbf1@W_rbf2 ----
__global__ void __launch_bounds__(256) k_prep(
    const float* __restrict__ W_kj, const float* __restrict__ W_down,
    const float* __restrict__ W_up, const float* __restrict__ W_ji,
    const float* __restrict__ W_get_up, const float* __restrict__ W_connect,
    const float* __restrict__ rbW, const float* __restrict__ W_lin,
    const float* __restrict__ raW,
    const float* __restrict__ W_rbf1, const float* __restrict__ W_rbf2,
    unsigned short* __restrict__ wreg) {
  int b = blockIdx.x;
  if (b == 13) {
    float* W12 = (float*)(wreg + OFF_END);
    for (int i = threadIdx.x; i < 768; i += 256) {
      int r = i >> 7, n = i & 127;
      float s = 0.f;
#pragma unroll
      for (int q = 0; q < 8; ++q) s += W_rbf1[r * 8 + q] * W_rbf2[q * 128 + n];
      W12[i] = s;
    }
    return;
  }
  const float* src; int K = 128, N = 128; int off;
  switch (b) {
    case 0:  src = W_kj;          off = OFF_KJ;  break;
    case 1:  src = W_down;        off = OFF_DOWN; N = 64;  break;
    case 2:  src = W_up;          off = OFF_UP;   K = 64;  break;
    case 3:  src = W_ji;          off = OFF_JI;  break;
    case 4:  src = W_get_up;      off = OFF_GU;  break;
    case 5:  src = W_connect;     off = OFF_CN;  break;
    case 6:  src = rbW;           off = OFF_RB0; break;
    case 7:  src = rbW + 16384;   off = OFF_RB1; break;
    case 8:  src = W_lin;         off = OFF_LIN; break;
    case 9:  src = raW;           off = OFF_RA00; break;
    case 10: src = raW + 16384;   off = OFF_RA01; break;
    case 11: src = raW + 32768;   off = OFF_RA10; break;
    default: src = raW + 49152;   off = OFF_RA11; break;
  }
  unsigned short* dst = wreg + off;
  int KS = K >> 5;
  for (int i = threadIdx.x; i < K * N; i += 256) {
    int k = i / N, n = i % N;
    int kk = k >> 5, kg = (k >> 3) & 3, j = k & 7;
    int nt = n >> 4, r15 = n & 15;
    dst[(((nt * KS + kk) * 4 + kg) << 7) + (r15 << 3) + j] = f2bf(src[i]);
  }
}

// ================= CSR build (by idx_ji) =================
__global__ void __launch_bounds__(256) k_hist(const int* __restrict__ idx_ji,
                                              int* __restrict__ counts) {
  int t = blockIdx.x * 256 + threadIdx.x;
  atomicAdd(&counts[idx_ji[t]], 1);
}

__global__ void __launch_bounds__(1024) k_scan1(const int* __restrict__ counts,
                                                int* __restrict__ locpre,
                                                int* __restrict__ bsum) {
  __shared__ int s[1024];
  int i = blockIdx.x * 1024 + threadIdx.x;
  int v = counts[i];
  s[threadIdx.x] = v; __syncthreads();
  for (int o = 1; o < 1024; o <<= 1) {
    int t = (threadIdx.x >= o) ? s[threadIdx.x - o] : 0;
    __syncthreads();
    s[threadIdx.x] += t;
    __syncthreads();
  }
  locpre[i] = s[threadIdx.x] - v;
  if (threadIdx.x == 1023) bsum[blockIdx.x] = s[1023];
}

__global__ void __launch_bounds__(256) k_scan2(const int* __restrict__ bsum,
                                               int* __restrict__ bpre, int* __restrict__ offs) {
  __shared__ int s[256];
  int v = bsum[threadIdx.x];
  s[threadIdx.x] = v; __syncthreads();
  for (int o = 1; o < 256; o <<= 1) {
    int t = (threadIdx.x >= o) ? s[threadIdx.x - o] : 0;
    __syncthreads();
    s[threadIdx.x] += t;
    __syncthreads();
  }
  bpre[threadIdx.x] = s[threadIdx.x] - v;
  if (threadIdx.x == 0) offs[E_N] = T_N;
}

__global__ void __launch_bounds__(1024) k_scan3(const int* __restrict__ locpre,
                                                const int* __restrict__ bpre,
                                                int* __restrict__ offs,
                                                int* __restrict__ pos) {
  int i = blockIdx.x * 1024 + threadIdx.x;
  int v = locpre[i] + bpre[blockIdx.x];
  offs[i] = v;
  pos[i] = v;
}

__global__ void __launch_bounds__(256) k_fill(const int* __restrict__ idx_ji,
                                              const int* __restrict__ idx_kj,
                                              int* __restrict__ pos,
                                              int* __restrict__ tri,
                                              int* __restrict__ inv,
                                              int* __restrict__ kjp) {
  int t = blockIdx.x * 256 + threadIdx.x;
  int e = idx_ji[t];
  int slot = atomicAdd(&pos[e], 1);
  tri[slot] = t;
  inv[t] = slot;
  kjp[slot] = idx_kj[t];
}

// ================= dense sbf_p -> CSR-slot order =================
__global__ void __launch_bounds__(256) k_sbfp(const float* __restrict__ sbf,
                                              const float* __restrict__ W_sbf1,
                                              const float* __restrict__ W_sbf2,
                                              const int* __restrict__ inv,
                                              unsigned int* __restrict__ sbfp) {
  __shared__ float s_s[336];
  __shared__ float s_t8[8][8];
  int t0 = blockIdx.x * 8;
  const float4* src = (const float4*)(sbf + (size_t)t0 * 42);
  for (int i = threadIdx.x; i < 84; i += 256)
    ((float4*)s_s)[i] = src[i];
  __syncthreads();
  if (threadIdx.x < 64) {
    int w8 = threadIdx.x >> 3, bb = threadIdx.x & 7;
    float s = 0.f;
#pragma unroll
    for (int r = 0; r < 42; ++r) s += s_s[w8 * 42 + r] * W_sbf1[r * 8 + bb];
    s_t8[w8][bb] = s;
  }
  __syncthreads();
  int w8 = threadIdx.x >> 5, jj = threadIdx.x & 31;
  float sp0 = 0.f, sp1 = 0.f;
#pragma unroll
  for (int bb = 0; bb < 8; ++bb) {
    float tv = s_t8[w8][bb];
    sp0 += tv * W_sbf2[bb * 64 + jj * 2];
    sp1 += tv * W_sbf2[bb * 64 + jj * 2 + 1];
  }
  int slot = inv[t0 + w8];
  sbfp[(size_t)slot * 32 + jj] = cvtpk(sp0, sp1);
}

// ================= gather: agg =================
__global__ void __launch_bounds__(256) k_aggB(const int* __restrict__ offs,
                                              const int* __restrict__ kjp,
                                              const unsigned int* __restrict__ sbfp,
                                              const unsigned int* __restrict__ xkj,
                                              unsigned int* __restrict__ agg) {
  int sub = threadIdx.x >> 5, jj = threadIdx.x & 31;
  int e = blockIdx.x * 8 + sub;
  int o0 = offs[e], o1 = offs[e + 1];
  float a0 = 0.f, a1 = 0.f;
  for (int i = o0; i < o1; ++i) {
    int kj = kjp[i];
    unsigned int sv = sbfp[(size_t)i * 32 + jj];
    unsigned int xv = xkj[(size_t)kj * 32 + jj];
    a0 += bf2f((unsigned short)(sv & 0xffff)) * bf2f((unsigned short)(xv & 0xffff));
    a1 += bf2f((unsigned short)(sv >> 16)) * bf2f((unsigned short)(xv >> 16));
  }
  agg[(size_t)e * 32 + jj] = cvtpk(a0, a1);
}

// ======= gather: x_up bf16 in-place (row stride 256 shorts) =======
__global__ void __launch_bounds__(256) k_xupg(const int* __restrict__ offs,
                                              const int* __restrict__ tri,
                                              const float* __restrict__ x1,
                                              unsigned int* __restrict__ out) {
  int sub = threadIdx.x >> 6, h2 = threadIdx.x & 63;
  int e = blockIdx.x * 4 + sub;
  int o0 = offs[e], o1 = offs[e + 1];
  float a0 = 0.f, a1 = 0.f;
  for (int i = o0; i < o1; ++i) {
    int t = tri[i];
    float2 v = *(const float2*)(x1 + (size_t)t * 128 + h2 * 2);
    a0 += v.x; a1 += v.y;
  }
  out[(size_t)e * 128 + h2] = cvtpk(a0, a1);
}

// ========== Phase A: swapped-D, 128-edge tile, 1024 thr ==========
__global__ void __launch_bounds__(1024, 4) phaseA(
    const float* __restrict__ x_old, const float* __restrict__ rbf0,
    const unsigned short* __restrict__ wreg,
    const float* __restrict__ b_kj, const float* __restrict__ b_down,
    unsigned short* __restrict__ xkjdown) {
  __shared__ char lds[65536];
  char* B0 = lds;
  char* B1 = lds + 32768;
  const int tid = threadIdx.x, lane = tid & 63, wave = tid >> 6;
  const int kg = lane >> 4, r15 = lane & 15;
  const int e0 = (wave & 7) * 16;
  const int ngrp = wave >> 3;                // 2 n-groups of 64
  const int nbase = ngrp * 64, ntb = ngrp * 4;
  const size_t e_base = (size_t)blockIdx.x * 128;
  const size_t e_lane = e_base + e0 + r15;
  const float* W12 = (const float*)(wreg + OFF_END);

  stage_tile<128, 128, 1024>(x_old + e_base * 128, B0);
  lds_barrier();

  f32x4 acc[4], val[4];
  mfma_gemm_T<4, 4, 256>(B0, e0, ntb, wreg + OFF_KJ, lane, acc);
  {
    float rp[6];
#pragma unroll
    for (int q = 0; q < 6; ++q) rp[q] = rbf0[e_lane * 6 + q];
#pragma unroll
    for (int m = 0; m < 4; ++m) {
      int n0 = nbase + m * 16 + kg * 4;
      f32x4 bk = *(const f32x4*)(b_kj + n0);
      f32x4 rv = (f32x4){0.f, 0.f, 0.f, 0.f};
#pragma unroll
      for (int q = 0; q < 6; ++q) {
        f32x4 w = *(const f32x4*)(W12 + q * 128 + n0);
#pragma unroll
        for (int r = 0; r < 4; ++r) rv[r] += rp[q] * w[r];
      }
      f32x4 s = silu4(acc[m] + bk);
#pragma unroll
      for (int r = 0; r < 4; ++r) val[m][r] = s[r] * rv[r];
    }
  }
  write_cd_T<4, 256>(B1, e0, nbase, lane, val);
  lds_barrier();

  // GEMM2: N=64, 2 n-groups of 32 (MREP=2)
  const int nb2 = (wave >> 3) * 32, nt2 = (wave >> 3) * 2;
  f32x4 a2[2];
  mfma_gemm_T<2, 4, 256>(B1, e0, nt2, wreg + OFF_DOWN, lane, a2);
#pragma unroll
  for (int m = 0; m < 2; ++m) {
    int n0 = nb2 + m * 16 + kg * 4;
    f32x4 bd = *(const f32x4*)(b_down + n0);
    f32x4 s = silu4(a2[m] + bd);
    uint2 u;
    u.x = cvtpk(s[0], s[1]);
    u.y = cvtpk(s[2], s[3]);
    *(uint2*)(xkjdown + e_lane * 64 + n0) = u;
  }
}

// ======== Phase C1: swapped-D chain, 128-edge tile, 1024 thr ========
__global__ void __launch_bounds__(1024, 4) phaseC1(
    const float* __restrict__ x_old, float* __restrict__ e1buf,
    const unsigned short* __restrict__ xup_b,
    const unsigned short* __restrict__ agg, const unsigned short* __restrict__ wreg,
    const float* __restrict__ b_up, const float* __restrict__ b_ji,
    const float* __restrict__ b_get_up, const float* __restrict__ b_connect,
    const float* __restrict__ rbB, const float* __restrict__ b_lin,
    const float* __restrict__ raB,
    const float* __restrict__ rbf0, const float* __restrict__ W_rbf,
    float* __restrict__ e2o) {
  __shared__ char lds[65536];
  char* X0 = lds;
  char* X1 = lds + 32768;
  const int tid = threadIdx.x, lane = tid & 63, wave = tid >> 6;
  const int kg = lane >> 4, r15 = lane & 15;
  const int e0 = (wave & 7) * 16;
  const int ngrp = wave >> 3;
  const int nbase = ngrp * 64, ntb = ngrp * 4;
  const size_t e_base = (size_t)blockIdx.x * 128;
  const size_t e_lane = e_base + e0 + r15;

  stage_tile<128, 128, 1024>(x_old + e_base * 128, X1);
  lds_barrier();                                                     // b0

  f32x4 acc[4], keep[4], h[4];

  // S1: h = silu(agg@W_up + b_up)   (B rows from global, K=64)
  mfma_gemm_T_gB<4, 2, 64>(agg, e_base + e0, ntb, wreg + OFF_UP, lane, acc);
#pragma unroll
  for (int m = 0; m < 4; ++m) {
    f32x4 b = *(const f32x4*)(b_up + nbase + m * 16 + kg * 4);
    h[m] = silu4(acc[m] + b);
  }
  // S2: keep = silu(X1@W_ji + b_ji) + h -> X0
  mfma_gemm_T<4, 4, 256>(X1, e0, ntb, wreg + OFF_JI, lane, acc);
#pragma unroll
  for (int m = 0; m < 4; ++m) {
    f32x4 b = *(const f32x4*)(b_ji + nbase + m * 16 + kg * 4);
    keep[m] = silu4(acc[m] + b) + h[m];
  }
  write_cd_T<4, 256>(X0, e0, nbase, lane, keep);
  lds_barrier();                                                     // b1

  // S3: h = silu(x_up@W_get_up + b)   (B rows from global, RS=256)
  mfma_gemm_T_gB<4, 4, 256>(xup_b, e_base + e0, ntb, wreg + OFF_GU, lane, acc);
#pragma unroll
  for (int m = 0; m < 4; ++m) {
    f32x4 b = *(const f32x4*)(b_get_up + nbase + m * 16 + kg * 4);
    h[m] = silu4(acc[m] + b);
  }
  // S4: keep = silu(X0@W_connect + b) + h -> X1
  mfma_gemm_T<4, 4, 256>(X0, e0, ntb, wreg + OFF_CN, lane, acc);
#pragma unroll
  for (int m = 0; m < 4; ++m) {
    f32x4 b = *(const f32x4*)(b_connect + nbase + m * 16 + kg * 4);
    keep[m] = silu4(acc[m] + b) + h[m];
  }
  write_cd_T<4, 256>(X1, e0, nbase, lane, keep);
  lds_barrier();                                                     // b2

  // S5: h = silu(X1@rb0 + b) -> X0
  mfma_gemm_T<4, 4, 256>(X1, e0, ntb, wreg + OFF_RB0, lane, acc);
#pragma unroll
  for (int m = 0; m < 4; ++m) {
    f32x4 b = *(const f32x4*)(rbB + nbase + m * 16 + kg * 4);
    h[m] = silu4(acc[m] + b);
  }
  write_cd_T<4, 256>(X0, e0, nbase, lane, h);
  lds_barrier();                                                     // b3

  // S6: keep += silu(X0@rb1 + b) -> X1
  mfma_gemm_T<4, 4, 256>(X0, e0, ntb, wreg + OFF_RB1, lane, acc);
#pragma unroll
  for (int m = 0; m < 4; ++m) {
    f32x4 b = *(const f32x4*)(rbB + 128 + nbase + m * 16 + kg * 4);
    keep[m] += silu4(acc[m] + b);
  }
  write_cd_T<4, 256>(X1, e0, nbase, lane, keep);
  lds_barrier();                                                     // b4

  // S7: keep = silu(X1@W_lin + b) + x_old -> X0
  mfma_gemm_T<4, 4, 256>(X1, e0, ntb, wreg + OFF_LIN, lane, acc);
#pragma unroll
  for (int m = 0; m < 4; ++m) {
    int n0 = nbase + m * 16 + kg * 4;
    f32x4 b = *(const f32x4*)(b_lin + n0);
    f32x4 xo = *(const f32x4*)(x_old + e_lane * 128 + n0);
    keep[m] = silu4(acc[m] + b) + xo;
  }
  write_cd_T<4, 256>(X0, e0, nbase, lane, keep);
  lds_barrier();                                                     // b5

  // S8: h = silu(X0@ra00 + b) -> X1
  mfma_gemm_T<4, 4, 256>(X0, e0, ntb, wreg + OFF_RA00, lane, acc);
#pragma unroll
  for (int m = 0; m < 4; ++m) {
    f32x4 b = *(const f32x4*)(raB + nbase + m * 16 + kg * 4);
    h[m] = silu4(acc[m] + b);
  }
  write_cd_T<4, 256>(X1, e0, nbase, lane, h);
  lds_barrier();                                                     // b6

  // S9: keep += silu(X1@ra01 + b) -> X0
  mfma_gemm_T<4, 4, 256>(X1, e0, ntb, wreg + OFF_RA01, lane, acc);
#pragma unroll
  for (int m = 0; m < 4; ++m) {
    f32x4 b = *(const f32x4*)(raB + 128 + nbase + m * 16 + kg * 4);
    keep[m] += silu4(acc[m] + b);
  }
  write_cd_T<4, 256>(X0, e0, nbase, lane, keep);
  lds_barrier();                                                     // b7

  // S10: h = silu(X0@ra10 + b) -> X1
  mfma_gemm_T<4, 4, 256>(X0, e0, ntb, wreg + OFF_RA10, lane, acc);
#pragma unroll
  for (int m = 0; m < 4; ++m) {
    f32x4 b = *(const f32x4*)(raB + 256 + nbase + m * 16 + kg * 4);
    h[m] = silu4(acc[m] + b);
  }
  write_cd_T<4, 256>(X1, e0, nbase, lane, h);
  lds_barrier();                                                     // b8

  // S11: e1 = keep + silu(X1@ra11 + b) -> global ; fused e2 (all float4)
  mfma_gemm_T<4, 4, 256>(X1, e0, ntb, wreg + OFF_RA11, lane, acc);
  {
    float rp[6];
    if (e2o) {
#pragma unroll
      for (int q = 0; q < 6; ++q) rp[q] = rbf0[e_lane * 6 + q];
    }
#pragma unroll
    for (int m = 0; m < 4; ++m) {
      int n0 = nbase + m * 16 + kg * 4;
      f32x4 b = *(const f32x4*)(raB + 384 + n0);
      f32x4 val = keep[m] + silu4(acc[m] + b);
      *(f32x4*)(e1buf + e_lane * 128 + n0) = val;
      if (e2o) {
        f32x4 rv = (f32x4){0.f, 0.f, 0.f, 0.f};
#pragma unroll
        for (int q = 0; q < 6; ++q) {
          f32x4 w = *(const f32x4*)(W_rbf + q * 128 + n0);
#pragma unroll
          for (int r = 0; r < 4; ++r) rv[r] += rp[q] * w[r];
        }
        f32x4 o;
#pragma unroll
        for (int r = 0; r < 4; ++r) o[r] = val[r] * rv[r];
        *(f32x4*)(e2o + e_lane * 128 + n0) = o;
      }
    }
  }
}

// ---- fallback C2 epilogue: e2 = (rbf0 @ W_rbf) * e1 ----
__global__ void __launch_bounds__(256) k_e2(const float* __restrict__ e1,
                                            const float* __restrict__ rbf0,
                                            const float* __restrict__ W_rbf,
                                            float* __restrict__ e2) {
  size_t gid = (size_t)blockIdx.x * 256 + threadIdx.x;
  int e = (int)(gid >> 5);
  int c = (int)(gid & 31) << 2;
  float r6[6];
#pragma unroll
  for (int r = 0; r < 6; ++r) r6[r] = rbf0[(size_t)e * 6 + r];
  float4 v = *(const float4*)(e1 + (size_t)e * 128 + c);
  float4 o;
  float rv;
  rv = 0.f;
#pragma unroll
  for (int r = 0; r < 6; ++r) rv += r6[r] * W_rbf[r * 128 + c + 0];
  o.x = v.x * rv;
  rv = 0.f;
#pragma unroll
  for (int r = 0; r < 6; ++r) rv += r6[r] * W_rbf[r * 128 + c + 1];
  o.y = v.y * rv;
  rv = 0.f;
#pragma unroll
  for (int r = 0; r < 6; ++r) rv += r6[r] * W_rbf[r * 128 + c + 2];
  o.z = v.z * rv;
  rv = 0.f;
#pragma unroll
  for (int r = 0; r < 6; ++r) rv += r6[r] * W_rbf[r * 128 + c + 3];
  o.w = v.w * rv;
  *(float4*)(e2 + (size_t)e * 128 + c) = o;
}

extern "C" void kernel_launch(void* const* d_in, const int* in_sizes, int n_in,
                              void* d_out, int out_size, void* d_ws, size_t ws_size,
                              hipStream_t stream) {
  const float* x1        = (const float*)d_in[0];
  const float* x_old     = (const float*)d_in[1];
  const float* rbf0      = (const float*)d_in[2];
  const float* sbf       = (const float*)d_in[3];
  const int*   idx_kj    = (const int*)d_in[4];
  const int*   idx_ji    = (const int*)d_in[5];
  const float* W_rbf1    = (const float*)d_in[6];
  const float* W_rbf2    = (const float*)d_in[7];
  const float* W_sbf1    = (const float*)d_in[8];
  const float* W_sbf2    = (const float*)d_in[9];
  const float* W_rbf     = (const float*)d_in[10];
  const float* W_kj      = (const float*)d_in[11];
  const float* b_kj      = (const float*)d_in[12];
  const float* W_ji      = (const float*)d_in[13];
  const float* b_ji      = (const float*)d_in[14];
  const float* W_connect = (const float*)d_in[15];
  const float* b_connect = (const float*)d_in[16];
  const float* W_get_up  = (const float*)d_in[17];
  const float* b_get_up  = (const float*)d_in[18];
  const float* W_down    = (const float*)d_in[19];
  const float* b_down    = (const float*)d_in[20];
  const float* W_up      = (const float*)d_in[21];
  const float* b_up      = (const float*)d_in[22];
  const float* rbW       = (const float*)d_in[23];
  const float* rbB       = (const float*)d_in[24];
  const float* W_lin     = (const float*)d_in[25];
  const float* b_lin     = (const float*)d_in[26];
  const float* raW       = (const float*)d_in[27];
  const float* raB       = (const float*)d_in[28];

  float* e1buf = (float*)d_out;
  char*  base2 = (char*)d_out + (size_t)E_N * 128 * 4;
  float* e2out = (float*)base2;

  unsigned short* xkj_b = (unsigned short*)(base2 + OFFB_XKJ);
  int* counts = (int*)(base2 + OFFB_CNT);
  int* pos    = (int*)(base2 + OFFB_POS);
  int* tri    = (int*)(base2 + OFFB_TRI);
  int* bsum   = (int*)(base2 + OFFB_BS);
  int* bpre   = (int*)(base2 + OFFB_BP);
  int* kjp    = (int*)(base2 + OFFB_KJP);
  int* inv    = (int*)(base2 + OFFB_INV);

  const size_t need_ws = (size_t)WREG_BYTES + (size_t)E_N * 64 * 2;
  const bool fuse = ws_size >= need_ws;
  unsigned short* wreg  = fuse ? (unsigned short*)d_ws
                               : (unsigned short*)(base2 + OFFB_WREG);
  unsigned short* agg_b = fuse ? (unsigned short*)((char*)d_ws + WREG_BYTES)
                               : (unsigned short*)(base2 + OFFB_AGG);

  unsigned int* sbfp_u = (unsigned int*)e1buf;
  unsigned int* xup_u  = (unsigned int*)e1buf;

  k_prep<<<14, 256, 0, stream>>>(W_kj, W_down, W_up, W_ji, W_get_up, W_connect,
                                 rbW, W_lin, raW, W_rbf1, W_rbf2, wreg);

  hipMemsetAsync(counts, 0, (E_N + 1) * sizeof(int), stream);
  k_hist<<<T_N / 256, 256, 0, stream>>>(idx_ji, counts);
  k_scan1<<<256, 1024, 0, stream>>>(counts, pos, bsum);
  k_scan2<<<1, 256, 0, stream>>>(bsum, bpre, counts);
  k_scan3<<<256, 1024, 0, stream>>>(pos, bpre, counts, pos);
  k_fill<<<T_N / 256, 256, 0, stream>>>(idx_ji, idx_kj, pos, tri, inv, kjp);

  k_sbfp<<<T_N / 8, 256, 0, stream>>>(sbf, W_sbf1, W_sbf2, inv, sbfp_u);

  phaseA<<<E_N / 128, 1024, 0, stream>>>(x_old, rbf0, wreg, b_kj, b_down, xkj_b);

  k_aggB<<<E_N / 8, 256, 0, stream>>>(counts, kjp, sbfp_u,
                                      (const unsigned int*)xkj_b, (unsigned int*)agg_b);

  k_xupg<<<E_N / 4, 256, 0, stream>>>(counts, tri, x1, xup_u);

  phaseC1<<<E_N / 128, 1024, 0, stream>>>(x_old, e1buf, (const unsigned short*)xup_u,
                                          agg_b, wreg,
                                          b_up, b_ji, b_get_up, b_connect, rbB, b_lin, raB,
                                          rbf0, W_rbf, fuse ? e2out : nullptr);
  if (!fuse)
    k_e2<<<E_N * 32 / 256, 256, 0, stream>>>(e1buf, rbf0, W_rbf, e2out);
}

// Round 17
// 1127.435 us; speedup vs baseline: 1.0547x; 1.0547x over previous
//
#include <hip/hip_runtime.h>

#define E_N 262144
#define T_N 1048576

typedef short  bf16x8  __attribute__((ext_vector_type(8)));
typedef float  f32x4   __attribute__((ext_vector_type(4)));

// wreg offsets (ushort units)
#define OFF_KJ    0
#define OFF_DOWN  16384
#define OFF_UP    24576
#define OFF_JI    32768
#define OFF_GU    49152
#define OFF_CN    65536
#define OFF_RB0   81920
#define OFF_RB1   98304
#define OFF_LIN   114688
#define OFF_RA00  131072
#define OFF_RA01  147456
#define OFF_RA10  163840
#define OFF_RA11  180224
#define OFF_END   196608   // W12 (f32[6][128]) follows
#define WREG_BYTES 524288u

// byte offsets inside the e2 slot (134217728 B)
#define OFFB_AGG   0u
#define OFFB_XKJ   33554432u
#define OFFB_WREG  67108864u
#define OFFB_CNT   67633152u
#define OFFB_POS   68683776u
#define OFFB_TRI   69732352u
#define OFFB_BS    73926656u
#define OFFB_BP    73927680u
#define OFFB_KJP   75497472u   // int [T] permuted idx_kj
#define OFFB_INV   79691776u   // int [T] t -> slot

// fast silu: x * rcp(1 + e^-x)
__device__ __forceinline__ float silu_f(float x) {
  float e;
  asm("v_exp_f32_e32 %0, %1" : "=v"(e) : "v"(x * -1.44269504088896f));
  float r;
  asm("v_rcp_f32_e32 %0, %1" : "=v"(r) : "v"(1.0f + e));
  return x * r;
}

__device__ __forceinline__ unsigned short f2bf(float f) {
  union { float f; unsigned int u; } v; v.f = f;
  unsigned int u = v.u;
  return (unsigned short)((u + 0x7fffu + ((u >> 16) & 1u)) >> 16);   // RNE
}
__device__ __forceinline__ float bf2f(unsigned short h) {
  union { unsigned int u; float f; } v; v.u = ((unsigned int)h) << 16;
  return v.f;
}

__device__ __forceinline__ unsigned cvtpk(float lo, float hi) {
  unsigned r;
  asm("v_cvt_pk_bf16_f32 %0, %1, %2" : "=v"(r) : "v"(lo), "v"(hi));
  return r;
}

// LDS-only barrier: waits ds ops (lgkmcnt) but lets GLOBAL loads stay in flight
// across the barrier. Cross-wave hazards here are LDS-only (X0/X1 ping-pong).
__device__ __forceinline__ void lds_barrier() {
  asm volatile("s_waitcnt lgkmcnt(0)" ::: "memory");
  __builtin_amdgcn_s_barrier();
  __builtin_amdgcn_sched_barrier(0);
}

// ---- stage [NR][NC] f32 global tile -> swizzled bf16 LDS tile (cvt_pk) ----
template<int NC, int NR, int NTH>
__device__ __forceinline__ void stage_tile(const float* __restrict__ g, char* __restrict__ lds) {
  constexpr int RB = NC * 2;
  constexpr int C4 = NC / 4;
  for (int i = threadIdx.x; i < NR * C4; i += NTH) {
    int r = i / C4, c4 = i % C4;
    float4 v = *(const float4*)(g + (size_t)r * NC + c4 * 4);
    uint2 u;
    u.x = cvtpk(v.x, v.y);
    u.y = cvtpk(v.z, v.w);
    *(uint2*)(lds + r * RB + ((c4 * 8) ^ ((r & 7) << 4))) = u;
  }
}

// Fragment-major weight layout: frag index = ((nt*KS + kk)*4 + kg)*128 + r15*8 + j

// ---- MFMA GEMM: swizzled LDS A-tile  @  WT fragment-major bf16 (global) ----
template<int MREP, int NREP, int KSTEPS, int RB>
__device__ __forceinline__ void mfma_gemm(const char* __restrict__ lds, int row0, int col0,
                                          const unsigned short* __restrict__ WT, int lane,
                                          f32x4 (&acc)[MREP][NREP]) {
  const int kg = lane >> 4, r15 = lane & 15;
#pragma unroll
  for (int m = 0; m < MREP; ++m)
#pragma unroll
    for (int n = 0; n < NREP; ++n) acc[m][n] = (f32x4){0.f, 0.f, 0.f, 0.f};
  __builtin_amdgcn_s_setprio(1);
#pragma unroll
  for (int kk = 0; kk < KSTEPS; ++kk) {
    bf16x8 a[MREP], bfr[NREP];
#pragma unroll
    for (int m = 0; m < MREP; ++m) {
      int row = row0 + m * 16 + r15;
      a[m] = *(const bf16x8*)(lds + row * RB + ((kk * 64 + kg * 16) ^ ((row & 7) << 4)));
    }
#pragma unroll
    for (int n = 0; n < NREP; ++n) {
      int nt = (col0 >> 4) + n;
      bfr[n] = *(const bf16x8*)(WT + (((nt * KSTEPS + kk) * 4 + kg) << 7) + (r15 << 3));
    }
#pragma unroll
    for (int m = 0; m < MREP; ++m)
#pragma unroll
      for (int n = 0; n < NREP; ++n)
        acc[m][n] = __builtin_amdgcn_mfma_f32_16x16x32_bf16(a[m], bfr[n], acc[m][n], 0, 0, 0);
  }
  __builtin_amdgcn_s_setprio(0);
}

// ---- MFMA GEMM with A-tile read directly from GLOBAL bf16 rows (stride RS shorts) ----
template<int MREP, int NREP, int KSTEPS, int RS>
__device__ __forceinline__ void mfma_gemm_gA(const unsigned short* __restrict__ gA,
                                             int row0, int col0,
                                             const unsigned short* __restrict__ WT, int lane,
                                             f32x4 (&acc)[MREP][NREP]) {
  const int kg = lane >> 4, r15 = lane & 15;
#pragma unroll
  for (int m = 0; m < MREP; ++m)
#pragma unroll
    for (int n = 0; n < NREP; ++n) acc[m][n] = (f32x4){0.f, 0.f, 0.f, 0.f};
  __builtin_amdgcn_s_setprio(1);
#pragma unroll
  for (int kk = 0; kk < KSTEPS; ++kk) {
    bf16x8 a[MREP], bfr[NREP];
#pragma unroll
    for (int m = 0; m < MREP; ++m)
      a[m] = *(const bf16x8*)(gA + (size_t)(row0 + m * 16 + r15) * RS + kk * 32 + kg * 8);
#pragma unroll
    for (int n = 0; n < NREP; ++n) {
      int nt = (col0 >> 4) + n;
      bfr[n] = *(const bf16x8*)(WT + (((nt * KSTEPS + kk) * 4 + kg) << 7) + (r15 << 3));
    }
#pragma unroll
    for (int m = 0; m < MREP; ++m)
#pragma unroll
      for (int n = 0; n < NREP; ++n)
        acc[m][n] = __builtin_amdgcn_mfma_f32_16x16x32_bf16(a[m], bfr[n], acc[m][n], 0, 0, 0);
  }
  __builtin_amdgcn_s_setprio(0);
}

// ---- write MREPxNREP fragment set (f32) as bf16 into swizzled LDS tile ----
template<int MREP, int NREP, int RB>
__device__ __forceinline__ void write_cd(char* __restrict__ lds, int wrow, int wcol, int lane,
                                         const f32x4 (&v)[MREP][NREP]) {
  const int kg = lane >> 4, r15 = lane & 15;
#pragma unroll
  for (int m = 0; m < MREP; ++m)
#pragma unroll
    for (int n = 0; n < NREP; ++n) {
      int col2 = (wcol + n * 16 + r15) * 2;
      int row0 = wrow + m * 16 + kg * 4;
      unsigned u0 = cvtpk(v[m][n][0], v[m][n][1]);
      unsigned u1 = cvtpk(v[m][n][2], v[m][n][3]);
      *(unsigned short*)(lds + (row0 + 0) * RB + (col2 ^ (((row0 + 0) & 7) << 4))) = (unsigned short)u0;
      *(unsigned short*)(lds + (row0 + 1) * RB + (col2 ^ (((row0 + 1) & 7) << 4))) = (unsigned short)(u0 >> 16);
      *(unsigned short*)(lds + (row0 + 2) * RB + (col2 ^ (((row0 + 2) & 7) << 4))) = (unsigned short)u1;
      *(unsigned short*)(lds + (row0 + 3) * RB + (col2 ^ (((row0 + 3) & 7) << 4))) = (unsigned short)(u1 >> 16);
    }
}

// ---- prep: weights -> fragment-major bf16; W12 = W_rbf1@W_rbf2 ----
__global__ void __launch_bounds__(256) k_prep(
    const float* __restrict__ W_kj, const float* __restrict__ W_down,
    const float* __restrict__ W_up, const float* __restrict__ W_ji,
    const float* __restrict__ W_get_up, const float* __restrict__ W_connect,
    const float* __restrict__ rbW, const float* __restrict__ W_lin,
    const float* __restrict__ raW,
    const float* __restrict__ W_rbf1, const float* __restrict__ W_rbf2,
    unsigned short* __restrict__ wreg) {
  int b = blockIdx.x;
  if (b == 13) {
    float* W12 = (float*)(wreg + OFF_END);
    for (int i = threadIdx.x; i < 768; i += 256) {
      int r = i >> 7, n = i & 127;
      float s = 0.f;
#pragma unroll
      for (int q = 0; q < 8; ++q) s += W_rbf1[r * 8 + q] * W_rbf2[q * 128 + n];
      W12[i] = s;
    }
    return;
  }
  const float* src; int K = 128, N = 128; int off;
  switch (b) {
    case 0:  src = W_kj;          off = OFF_KJ;  break;
    case 1:  src = W_down;        off = OFF_DOWN; N = 64;  break;
    case 2:  src = W_up;          off = OFF_UP;   K = 64;  break;
    case 3:  src = W_ji;          off = OFF_JI;  break;
    case 4:  src = W_get_up;      off = OFF_GU;  break;
    case 5:  src = W_connect;     off = OFF_CN;  break;
    case 6:  src = rbW;           off = OFF_RB0; break;
    case 7:  src = rbW + 16384;   off = OFF_RB1; break;
    case 8:  src = W_lin;         off = OFF_LIN; break;
    case 9:  src = raW;           off = OFF_RA00; break;
    case 10: src = raW + 16384;   off = OFF_RA01; break;
    case 11: src = raW + 32768;   off = OFF_RA10; break;
    default: src = raW + 49152;   off = OFF_RA11; break;
  }
  unsigned short* dst = wreg + off;
  int KS = K >> 5;
  for (int i = threadIdx.x; i < K * N; i += 256) {
    int k = i / N, n = i % N;
    int kk = k >> 5, kg = (k >> 3) & 3, j = k & 7;
    int nt = n >> 4, r15 = n & 15;
    dst[(((nt * KS + kk) * 4 + kg) << 7) + (r15 << 3) + j] = f2bf(src[i]);
  }
}

// ================= CSR build (by idx_ji) =================
__global__ void __launch_bounds__(256) k_hist(const int* __restrict__ idx_ji,
                                              int* __restrict__ counts) {
  int t = blockIdx.x * 256 + threadIdx.x;
  atomicAdd(&counts[idx_ji[t]], 1);
}

__global__ void __launch_bounds__(1024) k_scan1(const int* __restrict__ counts,
                                                int* __restrict__ locpre,
                                                int* __restrict__ bsum) {
  __shared__ int s[1024];
  int i = blockIdx.x * 1024 + threadIdx.x;
  int v = counts[i];
  s[threadIdx.x] = v; __syncthreads();
  for (int o = 1; o < 1024; o <<= 1) {
    int t = (threadIdx.x >= o) ? s[threadIdx.x - o] : 0;
    __syncthreads();
    s[threadIdx.x] += t;
    __syncthreads();
  }
  locpre[i] = s[threadIdx.x] - v;
  if (threadIdx.x == 1023) bsum[blockIdx.x] = s[1023];
}

__global__ void __launch_bounds__(256) k_scan2(const int* __restrict__ bsum,
                                               int* __restrict__ bpre, int* __restrict__ offs) {
  __shared__ int s[256];
  int v = bsum[threadIdx.x];
  s[threadIdx.x] = v; __syncthreads();
  for (int o = 1; o < 256; o <<= 1) {
    int t = (threadIdx.x >= o) ? s[threadIdx.x - o] : 0;
    __syncthreads();
    s[threadIdx.x] += t;
    __syncthreads();
  }
  bpre[threadIdx.x] = s[threadIdx.x] - v;
  if (threadIdx.x == 0) offs[E_N] = T_N;
}

__global__ void __launch_bounds__(1024) k_scan3(const int* __restrict__ locpre,
                                                const int* __restrict__ bpre,
                                                int* __restrict__ offs,
                                                int* __restrict__ pos) {
  int i = blockIdx.x * 1024 + threadIdx.x;
  int v = locpre[i] + bpre[blockIdx.x];
  offs[i] = v;
  pos[i] = v;
}

// fill: tri[slot]=t ; inv[t]=slot ; kjp[slot]=idx_kj[t]
__global__ void __launch_bounds__(256) k_fill(const int* __restrict__ idx_ji,
                                              const int* __restrict__ idx_kj,
                                              int* __restrict__ pos,
                                              int* __restrict__ tri,
                                              int* __restrict__ inv,
                                              int* __restrict__ kjp) {
  int t = blockIdx.x * 256 + threadIdx.x;
  int e = idx_ji[t];
  int slot = atomicAdd(&pos[e], 1);
  tri[slot] = t;
  inv[t] = slot;
  kjp[slot] = idx_kj[t];
}

// ================= dense sbf_p -> CSR-slot order: sbfp[inv[t]] =================
__global__ void __launch_bounds__(256) k_sbfp(const float* __restrict__ sbf,
                                              const float* __restrict__ W_sbf1,
                                              const float* __restrict__ W_sbf2,
                                              const int* __restrict__ inv,
                                              unsigned int* __restrict__ sbfp) {
  __shared__ float s_s[336];   // 8 rows x 42
  __shared__ float s_t8[8][8];
  int t0 = blockIdx.x * 8;
  const float4* src = (const float4*)(sbf + (size_t)t0 * 42);
  for (int i = threadIdx.x; i < 84; i += 256)
    ((float4*)s_s)[i] = src[i];
  __syncthreads();
  if (threadIdx.x < 64) {
    int w8 = threadIdx.x >> 3, bb = threadIdx.x & 7;
    float s = 0.f;
#pragma unroll
    for (int r = 0; r < 42; ++r) s += s_s[w8 * 42 + r] * W_sbf1[r * 8 + bb];
    s_t8[w8][bb] = s;
  }
  __syncthreads();
  int w8 = threadIdx.x >> 5, jj = threadIdx.x & 31;
  float sp0 = 0.f, sp1 = 0.f;
#pragma unroll
  for (int bb = 0; bb < 8; ++bb) {
    float tv = s_t8[w8][bb];
    sp0 += tv * W_sbf2[bb * 64 + jj * 2];
    sp1 += tv * W_sbf2[bb * 64 + jj * 2 + 1];
  }
  int slot = inv[t0 + w8];
  sbfp[(size_t)slot * 32 + jj] = cvtpk(sp0, sp1);
}

// ================= gather: agg[e][j] = sum_slot sbfp[slot][j]*xkj[kjp[slot]][j] =================
__global__ void __launch_bounds__(256) k_aggB(const int* __restrict__ offs,
                                              const int* __restrict__ kjp,
                                              const unsigned int* __restrict__ sbfp,
                                              const unsigned int* __restrict__ xkj,
                                              unsigned int* __restrict__ agg) {
  int sub = threadIdx.x >> 5, jj = threadIdx.x & 31;
  int e = blockIdx.x * 8 + sub;
  int o0 = offs[e], o1 = offs[e + 1];
  float a0 = 0.f, a1 = 0.f;
  for (int i = o0; i < o1; ++i) {
    int kj = kjp[i];
    unsigned int sv = sbfp[(size_t)i * 32 + jj];
    unsigned int xv = xkj[(size_t)kj * 32 + jj];
    a0 += bf2f((unsigned short)(sv & 0xffff)) * bf2f((unsigned short)(xv & 0xffff));
    a1 += bf2f((unsigned short)(sv >> 16)) * bf2f((unsigned short)(xv >> 16));
  }
  agg[(size_t)e * 32 + jj] = cvtpk(a0, a1);
}

// ======= gather: x_up bf16 in-place (row stride 256 shorts) =======
__global__ void __launch_bounds__(256) k_xupg(const int* __restrict__ offs,
                                              const int* __restrict__ tri,
                                              const float* __restrict__ x1,
                                              unsigned int* __restrict__ out) {
  int sub = threadIdx.x >> 6, h2 = threadIdx.x & 63;
  int e = blockIdx.x * 4 + sub;
  int o0 = offs[e], o1 = offs[e + 1];
  float a0 = 0.f, a1 = 0.f;
  for (int i = o0; i < o1; ++i) {
    int t = tri[i];
    float2 v = *(const float2*)(x1 + (size_t)t * 128 + h2 * 2);
    a0 += v.x; a1 += v.y;
  }
  out[(size_t)e * 128 + h2] = cvtpk(a0, a1);   // 128 uints stride = 512B row
}

// ========== Phase A: 128-edge tile, 1024 thr, 2 LDS-only barriers ==========
__global__ void __launch_bounds__(1024, 4) phaseA(
    const float* __restrict__ x_old, const float* __restrict__ rbf0,
    const unsigned short* __restrict__ wreg,
    const float* __restrict__ b_kj, const float* __restrict__ b_down,
    unsigned short* __restrict__ xkjdown) {
  __shared__ char lds[65536];
  char* B0 = lds;
  char* B1 = lds + 32768;
  const int tid = threadIdx.x, lane = tid & 63, wave = tid >> 6;
  const int kg = lane >> 4, r15 = lane & 15;
  const int wrow = (wave >> 3) * 64;
  const int wcol = (wave & 7) * 16;
  const size_t e_base = (size_t)blockIdx.x * 128;
  const float* W12 = (const float*)(wreg + OFF_END);

  stage_tile<128, 128, 1024>(x_old + e_base * 128, B0);
  lds_barrier();

  f32x4 acc[4][1], val[4][1];
  mfma_gemm<4, 1, 4, 256>(B0, wrow, wcol, wreg + OFF_KJ, lane, acc);
  {
    int col = wcol + r15;
    float bk = b_kj[col];
    float wc[6];
#pragma unroll
    for (int q = 0; q < 6; ++q) wc[q] = W12[q * 128 + col];
#pragma unroll
    for (int m = 0; m < 4; ++m)
#pragma unroll
      for (int r = 0; r < 4; ++r) {
        int row = wrow + m * 16 + kg * 4 + r;
        const float* rp = rbf0 + (e_base + row) * 6;
        float rv = rp[0]*wc[0] + rp[1]*wc[1] + rp[2]*wc[2] + rp[3]*wc[3] + rp[4]*wc[4] + rp[5]*wc[5];
        val[m][0][r] = silu_f(acc[m][0][r] + bk) * rv;
      }
  }
  write_cd<4, 1, 256>(B1, wrow, wcol, lane, val);
  lds_barrier();

  const int wrow2 = (wave >> 1) * 16, wcol2 = (wave & 1) * 32;
  f32x4 a2[1][2];
  mfma_gemm<1, 2, 4, 256>(B1, wrow2, wcol2, wreg + OFF_DOWN, lane, a2);
#pragma unroll
  for (int n = 0; n < 2; ++n) {
    int col = wcol2 + n * 16 + r15;
    float bd = b_down[col];
#pragma unroll
    for (int r = 0; r < 4; ++r) {
      int row = wrow2 + kg * 4 + r;
      xkjdown[(e_base + row) * 64 + col] = f2bf(silu_f(a2[0][n][r] + bd));
    }
  }
}

// ======== Phase C1: 128-edge tile, 1024 thr, LDS-only barriers ========
__global__ void __launch_bounds__(1024, 4) phaseC1(
    const float* __restrict__ x_old, float* __restrict__ e1buf,
    const unsigned short* __restrict__ xup_b,
    const unsigned short* __restrict__ agg, const unsigned short* __restrict__ wreg,
    const float* __restrict__ b_up, const float* __restrict__ b_ji,
    const float* __restrict__ b_get_up, const float* __restrict__ b_connect,
    const float* __restrict__ rbB, const float* __restrict__ b_lin,
    const float* __restrict__ raB,
    const float* __restrict__ rbf0, const float* __restrict__ W_rbf,
    float* __restrict__ e2o) {
  __shared__ char lds[65536];   // X0, X1 (32KB each)
  char* X0 = lds;
  char* X1 = lds + 32768;
  const int tid = threadIdx.x, lane = tid & 63, wave = tid >> 6;
  const int kg = lane >> 4, r15 = lane & 15;
  const int wrow = (wave >> 3) * 64;
  const int wcol = (wave & 7) * 16;
  const size_t e_base = (size_t)blockIdx.x * 128;

  stage_tile<128, 128, 1024>(x_old + e_base * 128, X1);
  lds_barrier();                                                     // b0

  f32x4 acc[4][1], keep[4][1], h[4][1];

  // S1: h = silu(agg@W_up + b_up)
  mfma_gemm_gA<4, 1, 2, 64>(agg + e_base * 64, wrow, wcol, wreg + OFF_UP, lane, acc);
#pragma unroll
  for (int m = 0; m < 4; ++m) {
    float bu = b_up[wcol + r15];
#pragma unroll
    for (int r = 0; r < 4; ++r) h[m][0][r] = silu_f(acc[m][0][r] + bu);
  }
  // S2: keep(e1a) = silu(X1(x_old)@W_ji + b_ji) + h -> X0
  mfma_gemm<4, 1, 4, 256>(X1, wrow, wcol, wreg + OFF_JI, lane, acc);
  {
    float bj = b_ji[wcol + r15];
#pragma unroll
    for (int m = 0; m < 4; ++m)
#pragma unroll
      for (int r = 0; r < 4; ++r) keep[m][0][r] = silu_f(acc[m][0][r] + bj) + h[m][0][r];
  }
  write_cd<4, 1, 256>(X0, wrow, wcol, lane, keep);
  lds_barrier();                                                     // b1

  // S3: h = silu(x_up@W_get_up + b)
  mfma_gemm_gA<4, 1, 4, 256>(xup_b + e_base * 256, wrow, wcol, wreg + OFF_GU, lane, acc);
  {
    float bg = b_get_up[wcol + r15];
#pragma unroll
    for (int m = 0; m < 4; ++m)
#pragma unroll
      for (int r = 0; r < 4; ++r) h[m][0][r] = silu_f(acc[m][0][r] + bg);
  }
  // S4: keep(e1b) = silu(X0@W_connect + b) + h -> X1
  mfma_gemm<4, 1, 4, 256>(X0, wrow, wcol, wreg + OFF_CN, lane, acc);
  {
    float bc = b_connect[wcol + r15];
#pragma unroll
    for (int m = 0; m < 4; ++m)
#pragma unroll
      for (int r = 0; r < 4; ++r) keep[m][0][r] = silu_f(acc[m][0][r] + bc) + h[m][0][r];
  }
  write_cd<4, 1, 256>(X1, wrow, wcol, lane, keep);
  lds_barrier();                                                     // b2

  // S5: h = silu(X1@rb0 + b) -> X0
  mfma_gemm<4, 1, 4, 256>(X1, wrow, wcol, wreg + OFF_RB0, lane, acc);
  {
    float bv = rbB[wcol + r15];
#pragma unroll
    for (int m = 0; m < 4; ++m)
#pragma unroll
      for (int r = 0; r < 4; ++r) h[m][0][r] = silu_f(acc[m][0][r] + bv);
  }
  write_cd<4, 1, 256>(X0, wrow, wcol, lane, h);
  lds_barrier();                                                     // b3

  // S6: keep(e1c) += silu(X0@rb1 + b) -> X1
  mfma_gemm<4, 1, 4, 256>(X0, wrow, wcol, wreg + OFF_RB1, lane, acc);
  {
    float bv = rbB[128 + wcol + r15];
#pragma unroll
    for (int m = 0; m < 4; ++m)
#pragma unroll
      for (int r = 0; r < 4; ++r) keep[m][0][r] += silu_f(acc[m][0][r] + bv);
  }
  write_cd<4, 1, 256>(X1, wrow, wcol, lane, keep);
  lds_barrier();                                                     // b4

  // S7: keep(e1d) = silu(X1@W_lin + b) + x_old(global) -> X0
  mfma_gemm<4, 1, 4, 256>(X1, wrow, wcol, wreg + OFF_LIN, lane, acc);
  {
    int col = wcol + r15;
    float bl = b_lin[col];
#pragma unroll
    for (int m = 0; m < 4; ++m)
#pragma unroll
      for (int r = 0; r < 4; ++r) {
        int row = wrow + m * 16 + kg * 4 + r;
        keep[m][0][r] = silu_f(acc[m][0][r] + bl) + x_old[(e_base + row) * 128 + col];
      }
  }
  write_cd<4, 1, 256>(X0, wrow, wcol, lane, keep);
  lds_barrier();                                                     // b5

  // S8: h = silu(X0@ra00 + b) -> X1
  mfma_gemm<4, 1, 4, 256>(X0, wrow, wcol, wreg + OFF_RA00, lane, acc);
  {
    float bv = raB[wcol + r15];
#pragma unroll
    for (int m = 0; m < 4; ++m)
#pragma unroll
      for (int r = 0; r < 4; ++r) h[m][0][r] = silu_f(acc[m][0][r] + bv);
  }
  write_cd<4, 1, 256>(X1, wrow, wcol, lane, h);
  lds_barrier();                                                     // b6

  // S9: keep(e1e) += silu(X1@ra01 + b) -> X0
  mfma_gemm<4, 1, 4, 256>(X1, wrow, wcol, wreg + OFF_RA01, lane, acc);
  {
    float bv = raB[128 + wcol + r15];
#pragma unroll
    for (int m = 0; m < 4; ++m)
#pragma unroll
      for (int r = 0; r < 4; ++r) keep[m][0][r] += silu_f(acc[m][0][r] + bv);
  }
  write_cd<4, 1, 256>(X0, wrow, wcol, lane, keep);
  lds_barrier();                                                     // b7

  // S10: h = silu(X0@ra10 + b) -> X1
  mfma_gemm<4, 1, 4, 256>(X0, wrow, wcol, wreg + OFF_RA10, lane, acc);
  {
    float bv = raB[256 + wcol + r15];
#pragma unroll
    for (int m = 0; m < 4; ++m)
#pragma unroll
      for (int r = 0; r < 4; ++r) h[m][0][r] = silu_f(acc[m][0][r] + bv);
  }
  write_cd<4, 1, 256>(X1, wrow, wcol, lane, h);
  lds_barrier();                                                     // b8

  // S11: e1 = keep + silu(X1@ra11 + b) -> global ; fused e2
  mfma_gemm<4, 1, 4, 256>(X1, wrow, wcol, wreg + OFF_RA11, lane, acc);
  {
    int col = wcol + r15;
    float bv = raB[384 + col];
    float wc[6];
#pragma unroll
    for (int q = 0; q < 6; ++q) wc[q] = W_rbf[q * 128 + col];
#pragma unroll
    for (int m = 0; m < 4; ++m)
#pragma unroll
      for (int r = 0; r < 4; ++r) {
        int row = wrow + m * 16 + kg * 4 + r;
        size_t e = e_base + row;
        float val = keep[m][0][r] + silu_f(acc[m][0][r] + bv);
        e1buf[e * 128 + col] = val;
        if (e2o) {
          const float* rp = rbf0 + e * 6;
          float rv = rp[0]*wc[0] + rp[1]*wc[1] + rp[2]*wc[2] + rp[3]*wc[3] + rp[4]*wc[4] + rp[5]*wc[5];
          e2o[e * 128 + col] = val * rv;
        }
      }
  }
}

// ---- fallback C2 epilogue: e2 = (rbf0 @ W_rbf) * e1 ----
__global__ void __launch_bounds__(256) k_e2(const float* __restrict__ e1,
                                            const float* __restrict__ rbf0,
                                            const float* __restrict__ W_rbf,
                                            float* __restrict__ e2) {
  size_t gid = (size_t)blockIdx.x * 256 + threadIdx.x;
  int e = (int)(gid >> 5);
  int c = (int)(gid & 31) << 2;
  float r6[6];
#pragma unroll
  for (int r = 0; r < 6; ++r) r6[r] = rbf0[(size_t)e * 6 + r];
  float4 v = *(const float4*)(e1 + (size_t)e * 128 + c);
  float4 o;
  float rv;
  rv = 0.f;
#pragma unroll
  for (int r = 0; r < 6; ++r) rv += r6[r] * W_rbf[r * 128 + c + 0];
  o.x = v.x * rv;
  rv = 0.f;
#pragma unroll
  for (int r = 0; r < 6; ++r) rv += r6[r] * W_rbf[r * 128 + c + 1];
  o.y = v.y * rv;
  rv = 0.f;
#pragma unroll
  for (int r = 0; r < 6; ++r) rv += r6[r] * W_rbf[r * 128 + c + 2];
  o.z = v.z * rv;
  rv = 0.f;
#pragma unroll
  for (int r = 0; r < 6; ++r) rv += r6[r] * W_rbf[r * 128 + c + 3];
  o.w = v.w * rv;
  *(float4*)(e2 + (size_t)e * 128 + c) = o;
}

extern "C" void kernel_launch(void* const* d_in, const int* in_sizes, int n_in,
                              void* d_out, int out_size, void* d_ws, size_t ws_size,
                              hipStream_t stream) {
  const float* x1        = (const float*)d_in[0];
  const float* x_old     = (const float*)d_in[1];
  const float* rbf0      = (const float*)d_in[2];
  const float* sbf       = (const float*)d_in[3];
  const int*   idx_kj    = (const int*)d_in[4];
  const int*   idx_ji    = (const int*)d_in[5];
  const float* W_rbf1    = (const float*)d_in[6];
  const float* W_rbf2    = (const float*)d_in[7];
  const float* W_sbf1    = (const float*)d_in[8];
  const float* W_sbf2    = (const float*)d_in[9];
  const float* W_rbf     = (const float*)d_in[10];
  const float* W_kj      = (const float*)d_in[11];
  const float* b_kj      = (const float*)d_in[12];
  const float* W_ji      = (const float*)d_in[13];
  const float* b_ji      = (const float*)d_in[14];
  const float* W_connect = (const float*)d_in[15];
  const float* b_connect = (const float*)d_in[16];
  const float* W_get_up  = (const float*)d_in[17];
  const float* b_get_up  = (const float*)d_in[18];
  const float* W_down    = (const float*)d_in[19];
  const float* b_down    = (const float*)d_in[20];
  const float* W_up      = (const float*)d_in[21];
  const float* b_up      = (const float*)d_in[22];
  const float* rbW       = (const float*)d_in[23];
  const float* rbB       = (const float*)d_in[24];
  const float* W_lin     = (const float*)d_in[25];
  const float* b_lin     = (const float*)d_in[26];
  const float* raW       = (const float*)d_in[27];
  const float* raB       = (const float*)d_in[28];

  float* e1buf = (float*)d_out;                      // sbf_p -> x_up(bf16) -> e1
  char*  base2 = (char*)d_out + (size_t)E_N * 128 * 4;
  float* e2out = (float*)base2;

  unsigned short* xkj_b = (unsigned short*)(base2 + OFFB_XKJ);
  int* counts = (int*)(base2 + OFFB_CNT);
  int* pos    = (int*)(base2 + OFFB_POS);
  int* tri    = (int*)(base2 + OFFB_TRI);
  int* bsum   = (int*)(base2 + OFFB_BS);
  int* bpre   = (int*)(base2 + OFFB_BP);
  int* kjp    = (int*)(base2 + OFFB_KJP);
  int* inv    = (int*)(base2 + OFFB_INV);

  const size_t need_ws = (size_t)WREG_BYTES + (size_t)E_N * 64 * 2;
  const bool fuse = ws_size >= need_ws;
  unsigned short* wreg  = fuse ? (unsigned short*)d_ws
                               : (unsigned short*)(base2 + OFFB_WREG);
  unsigned short* agg_b = fuse ? (unsigned short*)((char*)d_ws + WREG_BYTES)
                               : (unsigned short*)(base2 + OFFB_AGG);

  unsigned int* sbfp_u = (unsigned int*)e1buf;   // bf16x2 [T][32] transient in e1 slot
  unsigned int* xup_u  = (unsigned int*)e1buf;   // bf16 x_up, row stride 512B, in e1 slot

  k_prep<<<14, 256, 0, stream>>>(W_kj, W_down, W_up, W_ji, W_get_up, W_connect,
                                 rbW, W_lin, raW, W_rbf1, W_rbf2, wreg);

  hipMemsetAsync(counts, 0, (E_N + 1) * sizeof(int), stream);
  k_hist<<<T_N / 256, 256, 0, stream>>>(idx_ji, counts);
  k_scan1<<<256, 1024, 0, stream>>>(counts, pos, bsum);
  k_scan2<<<1, 256, 0, stream>>>(bsum, bpre, counts);
  k_scan3<<<256, 1024, 0, stream>>>(pos, bpre, counts, pos);
  k_fill<<<T_N / 256, 256, 0, stream>>>(idx_ji, idx_kj, pos, tri, inv, kjp);

  k_sbfp<<<T_N / 8, 256, 0, stream>>>(sbf, W_sbf1, W_sbf2, inv, sbfp_u);

  phaseA<<<E_N / 128, 1024, 0, stream>>>(x_old, rbf0, wreg, b_kj, b_down, xkj_b);

  k_aggB<<<E_N / 8, 256, 0, stream>>>(counts, kjp, sbfp_u,
                                      (const unsigned int*)xkj_b, (unsigned int*)agg_b);

  k_xupg<<<E_N / 4, 256, 0, stream>>>(counts, tri, x1, xup_u);

  phaseC1<<<E_N / 128, 1024, 0, stream>>>(x_old, e1buf, (const unsigned short*)xup_u,
                                          agg_b, wreg,
                                          b_up, b_ji, b_get_up, b_connect, rbB, b_lin, raB,
                                          rbf0, W_rbf, fuse ? e2out : nullptr);
  if (!fuse)
    k_e2<<<E_N * 32 / 256, 256, 0, stream>>>(e1buf, rbf0, W_rbf, e2out);
}